// Round 2
// baseline (117.976 us; speedup 1.0000x reference)
//
#include <hip/hip_runtime.h>
#include <math.h>

#define B_TOK 8192
#define NB 4
#define CH 2048
#define TPB 256
#define TOK_PER_BLK 4
#define NBLK (B_TOK / TOK_PER_BLK)
#define SINK_ITERS 20
#define EPS 1e-5f

__device__ __forceinline__ float bcast_first(float v) {
    return __uint_as_float(__builtin_amdgcn_readfirstlane(__float_as_uint(v)));
}

// Fully fused: per-block redundant 4x4 Sinkhorn (uniform -> SGPRs via
// readfirstlane), then 4 tokens per block of RMSNorm + aggregate + mix.
// x read exactly once, y written exactly once. No workspace needed.
__global__ __launch_bounds__(TPB) void mhc_fused(
    const float* __restrict__ x,
    const float* __restrict__ w,
    const float* __restrict__ H_pre,
    const float* __restrict__ H_post,
    const float* __restrict__ H_res,
    float* __restrict__ y)
{
    const int t = threadIdx.x;
    const int wave = t >> 6;
    const int lane = t & 63;

    // rmsnorm weight for this thread's 8 channels (reused across all tokens)
    const float4* wv4 = (const float4*)w;
    float4 w0 = wv4[t], w1 = wv4[TPB + t];

    // ---- Sinkhorn on 4x4 (uniform across threads; overlaps load latency) ----
    float M[NB][NB];
    #pragma unroll
    for (int i = 0; i < NB; ++i)
        #pragma unroll
        for (int j = 0; j < NB; ++j)
            M[i][j] = expf(H_res[i * NB + j]);

    for (int s = 0; s < SINK_ITERS; ++s) {
        #pragma unroll
        for (int i = 0; i < NB; ++i) {
            float r = 1.0f / (M[i][0] + M[i][1] + M[i][2] + M[i][3] + EPS);
            #pragma unroll
            for (int j = 0; j < NB; ++j) M[i][j] *= r;
        }
        #pragma unroll
        for (int j = 0; j < NB; ++j) {
            float r = 1.0f / (M[0][j] + M[1][j] + M[2][j] + M[3][j] + EPS);
            #pragma unroll
            for (int i = 0; i < NB; ++i) M[i][j] *= r;
        }
    }

    // Move uniform mixing scalars to SGPRs (frees ~24 VGPRs)
    float H[NB][NB], pre[NB], post[NB];
    #pragma unroll
    for (int i = 0; i < NB; ++i)
        #pragma unroll
        for (int j = 0; j < NB; ++j)
            H[i][j] = bcast_first(M[i][j]);
    #pragma unroll
    for (int n = 0; n < NB; ++n) {
        pre[n]  = bcast_first(1.0f / (1.0f + expf(-H_pre[n])));
        post[n] = bcast_first(1.0f / (1.0f + expf(-H_post[n])));
    }

    __shared__ float red[4][NB];

    for (int it = 0; it < TOK_PER_BLK; ++it) {
        const int b = blockIdx.x * TOK_PER_BLK + it;

        // Load x[b, n, :]: per branch two coalesced float4 chunks
        const float4* xb = (const float4*)(x + (size_t)b * NB * CH);
        float4 xv[NB][2];
        float ss[NB];
        #pragma unroll
        for (int n = 0; n < NB; ++n) {
            xv[n][0] = xb[n * (CH / 4) + t];
            xv[n][1] = xb[n * (CH / 4) + TPB + t];
            float4 a = xv[n][0], c = xv[n][1];
            ss[n] = a.x * a.x + a.y * a.y + a.z * a.z + a.w * a.w +
                    c.x * c.x + c.y * c.y + c.z * c.z + c.w * c.w;
        }

        // Wave butterfly reduce, then 4-wave combine via LDS
        #pragma unroll
        for (int m = 1; m < 64; m <<= 1) {
            #pragma unroll
            for (int n = 0; n < NB; ++n)
                ss[n] += __shfl_xor(ss[n], m);
        }
        if (lane == 0) {
            #pragma unroll
            for (int n = 0; n < NB; ++n) red[wave][n] = ss[n];
        }
        __syncthreads();

        float inv[NB];
        #pragma unroll
        for (int n = 0; n < NB; ++n) {
            float tot = red[0][n] + red[1][n] + red[2][n] + red[3][n];
            inv[n] = rsqrtf(tot * (1.0f / CH) + EPS);
        }
        __syncthreads();   // allow red[] reuse next iteration

        // Unpack to [branch][8] registers (all-static indexing)
        float xr[NB][8];
        #pragma unroll
        for (int n = 0; n < NB; ++n) {
            xr[n][0] = xv[n][0].x; xr[n][1] = xv[n][0].y;
            xr[n][2] = xv[n][0].z; xr[n][3] = xv[n][0].w;
            xr[n][4] = xv[n][1].x; xr[n][5] = xv[n][1].y;
            xr[n][6] = xv[n][1].z; xr[n][7] = xv[n][1].w;
        }
        float wv[8] = { w0.x, w0.y, w0.z, w0.w, w1.x, w1.y, w1.z, w1.w };

        // x_agg[c] = sum_n pre[n] * x_norm[n][c]
        float agg[8];
        #pragma unroll
        for (int k = 0; k < 8; ++k) {
            float a = 0.0f;
            #pragma unroll
            for (int n = 0; n < NB; ++n)
                a += pre[n] * (xr[n][k] * inv[n] * wv[k]);
            agg[k] = a;
        }

        // y[b][m][c] = sum_n H[m][n]*x[n][c] + post[m]*agg[c]
        float4* yb = (float4*)(y + (size_t)b * NB * CH);
        #pragma unroll
        for (int m = 0; m < NB; ++m) {
            float out[8];
            #pragma unroll
            for (int k = 0; k < 8; ++k) {
                float v = post[m] * agg[k];
                #pragma unroll
                for (int n = 0; n < NB; ++n)
                    v += H[m][n] * xr[n][k];
                out[k] = v;
            }
            float4 o0 = { out[0], out[1], out[2], out[3] };
            float4 o1 = { out[4], out[5], out[6], out[7] };
            yb[m * (CH / 4) + t]       = o0;
            yb[m * (CH / 4) + TPB + t] = o1;
        }
    }
}

extern "C" void kernel_launch(void* const* d_in, const int* in_sizes, int n_in,
                              void* d_out, int out_size, void* d_ws, size_t ws_size,
                              hipStream_t stream) {
    const float* x      = (const float*)d_in[0];   // [B, N, C]
    const float* wgt    = (const float*)d_in[1];   // [C]
    const float* h_pre  = (const float*)d_in[2];   // [N]
    const float* h_post = (const float*)d_in[3];   // [N]
    const float* h_res  = (const float*)d_in[4];   // [N, N]
    float* y = (float*)d_out;                      // [B, N, C]

    mhc_fused<<<NBLK, TPB, 0, stream>>>(x, wgt, h_pre, h_post, h_res, y);
}

// Round 3
// 109.994 us; speedup vs baseline: 1.0726x; 1.0726x over previous
//
#include <hip/hip_runtime.h>
#include <math.h>

#define B_TOK 8192
#define NB 4
#define CH 2048
#define TPB 512           // 8 waves/block; 4 ch/thread
#define SINK_ITERS 20
#define EPS 1e-5f

// Kernel 1: tiny 4x4 Sinkhorn + sigmoids -> 24 floats in workspace.
// ws[0..15] = H (row-major), ws[16..19] = pre, ws[20..23] = post
__global__ void mhc_sinkhorn(const float* __restrict__ H_pre,
                             const float* __restrict__ H_post,
                             const float* __restrict__ H_res,
                             float* __restrict__ ws)
{
    if (threadIdx.x == 0) {
        float M[NB][NB];
        #pragma unroll
        for (int i = 0; i < NB; ++i)
            #pragma unroll
            for (int j = 0; j < NB; ++j)
                M[i][j] = expf(H_res[i * NB + j]);

        for (int it = 0; it < SINK_ITERS; ++it) {
            #pragma unroll
            for (int i = 0; i < NB; ++i) {
                float r = 1.0f / (M[i][0] + M[i][1] + M[i][2] + M[i][3] + EPS);
                #pragma unroll
                for (int j = 0; j < NB; ++j) M[i][j] *= r;
            }
            #pragma unroll
            for (int j = 0; j < NB; ++j) {
                float r = 1.0f / (M[0][j] + M[1][j] + M[2][j] + M[3][j] + EPS);
                #pragma unroll
                for (int i = 0; i < NB; ++i) M[i][j] *= r;
            }
        }
        #pragma unroll
        for (int i = 0; i < NB; ++i)
            #pragma unroll
            for (int j = 0; j < NB; ++j)
                ws[i * NB + j] = M[i][j];
        #pragma unroll
        for (int n = 0; n < NB; ++n) {
            ws[16 + n] = 1.0f / (1.0f + expf(-H_pre[n]));
            ws[20 + n] = 1.0f / (1.0f + expf(-H_post[n]));
        }
    }
}

// Kernel 2: one token per 512-thread block, 4 channels (one float4) per
// thread per branch. Low VGPR (~50) -> 8 waves/SIMD for max latency hiding.
// x read exactly once, y written exactly once.
__global__ __launch_bounds__(TPB) void mhc_main(const float* __restrict__ x,
                                                const float* __restrict__ w,
                                                const float* __restrict__ ws,
                                                float* __restrict__ y)
{
    const int b = blockIdx.x;
    const int t = threadIdx.x;
    const int wave = t >> 6;
    const int lane = t & 63;

    // Uniform mixing scalars: constant offsets from a kernel-arg pointer
    // -> scalar loads into SGPRs.
    float H[NB][NB], pre[NB], post[NB];
    #pragma unroll
    for (int i = 0; i < NB; ++i)
        #pragma unroll
        for (int j = 0; j < NB; ++j)
            H[i][j] = ws[i * NB + j];
    #pragma unroll
    for (int n = 0; n < NB; ++n) {
        pre[n]  = ws[16 + n];
        post[n] = ws[20 + n];
    }

    // Load: one float4 per branch (coalesced: thread t -> float4 t of the row)
    const float4* xb = (const float4*)(x + (size_t)b * NB * CH);
    float4 x0 = xb[0 * (CH / 4) + t];
    float4 x1 = xb[1 * (CH / 4) + t];
    float4 x2 = xb[2 * (CH / 4) + t];
    float4 x3 = xb[3 * (CH / 4) + t];

    // rmsnorm weight for this thread's 4 channels
    float4 wv = ((const float4*)w)[t];

    // Per-branch sum of squares (4 channels each)
    float ss[NB];
    ss[0] = x0.x * x0.x + x0.y * x0.y + x0.z * x0.z + x0.w * x0.w;
    ss[1] = x1.x * x1.x + x1.y * x1.y + x1.z * x1.z + x1.w * x1.w;
    ss[2] = x2.x * x2.x + x2.y * x2.y + x2.z * x2.z + x2.w * x2.w;
    ss[3] = x3.x * x3.x + x3.y * x3.y + x3.z * x3.z + x3.w * x3.w;

    // Wave butterfly reduce, then 8-wave combine via LDS
    #pragma unroll
    for (int m = 1; m < 64; m <<= 1) {
        #pragma unroll
        for (int n = 0; n < NB; ++n)
            ss[n] += __shfl_xor(ss[n], m);
    }
    __shared__ float red[TPB / 64][NB];
    if (lane == 0) {
        #pragma unroll
        for (int n = 0; n < NB; ++n) red[wave][n] = ss[n];
    }
    __syncthreads();

    // s_n = pre[n] * inv_rms[n]  (block-uniform)
    float s[NB];
    #pragma unroll
    for (int n = 0; n < NB; ++n) {
        float tot = red[0][n] + red[1][n] + red[2][n] + red[3][n] +
                    red[4][n] + red[5][n] + red[6][n] + red[7][n];
        s[n] = pre[n] * rsqrtf(tot * (1.0f / CH) + EPS);
    }

    // u = sum_n s_n * x_n ; wu = w ⊙ u  (agg scaled by weight, factored)
    float4 wu;
    wu.x = wv.x * (s[0] * x0.x + s[1] * x1.x + s[2] * x2.x + s[3] * x3.x);
    wu.y = wv.y * (s[0] * x0.y + s[1] * x1.y + s[2] * x2.y + s[3] * x3.y);
    wu.z = wv.z * (s[0] * x0.z + s[1] * x1.z + s[2] * x2.z + s[3] * x3.z);
    wu.w = wv.w * (s[0] * x0.w + s[1] * x1.w + s[2] * x2.w + s[3] * x3.w);

    // y[b][m] = sum_n H[m][n]*x_n + post[m] * wu
    float4* yb = (float4*)(y + (size_t)b * NB * CH);
    #pragma unroll
    for (int m = 0; m < NB; ++m) {
        float4 o;
        o.x = H[m][0] * x0.x + H[m][1] * x1.x + H[m][2] * x2.x + H[m][3] * x3.x + post[m] * wu.x;
        o.y = H[m][0] * x0.y + H[m][1] * x1.y + H[m][2] * x2.y + H[m][3] * x3.y + post[m] * wu.y;
        o.z = H[m][0] * x0.z + H[m][1] * x1.z + H[m][2] * x2.z + H[m][3] * x3.z + post[m] * wu.z;
        o.w = H[m][0] * x0.w + H[m][1] * x1.w + H[m][2] * x2.w + H[m][3] * x3.w + post[m] * wu.w;
        yb[m * (CH / 4) + t] = o;
    }
}

extern "C" void kernel_launch(void* const* d_in, const int* in_sizes, int n_in,
                              void* d_out, int out_size, void* d_ws, size_t ws_size,
                              hipStream_t stream) {
    const float* x      = (const float*)d_in[0];   // [B, N, C]
    const float* wgt    = (const float*)d_in[1];   // [C]
    const float* h_pre  = (const float*)d_in[2];   // [N]
    const float* h_post = (const float*)d_in[3];   // [N]
    const float* h_res  = (const float*)d_in[4];   // [N, N]
    float* y  = (float*)d_out;                     // [B, N, C]
    float* ws = (float*)d_ws;                      // >= 24 floats

    mhc_sinkhorn<<<1, 64, 0, stream>>>(h_pre, h_post, h_res, ws);
    mhc_main<<<B_TOK, TPB, 0, stream>>>(x, wgt, ws, y);
}

// Round 5
// 108.172 us; speedup vs baseline: 1.0906x; 1.0168x over previous
//
#include <hip/hip_runtime.h>
#include <math.h>

#define B_TOK 8192
#define NB 4
#define CH 2048
#define TPB 512            // 8 waves/block
#define NBLK 1024          // 4 blocks/CU, 8 tokens each
#define TOK_PER_BLK 8
#define SINK_ITERS 20
#define EPS 1e-5f

typedef float f32x4 __attribute__((ext_vector_type(4)));  // builtin-compatible

// Kernel 1: tiny 4x4 Sinkhorn + sigmoids -> 24 floats in workspace.
// ws[0..15] = H (row-major), ws[16..19] = pre, ws[20..23] = post
__global__ void mhc_sinkhorn(const float* __restrict__ H_pre,
                             const float* __restrict__ H_post,
                             const float* __restrict__ H_res,
                             float* __restrict__ ws)
{
    if (threadIdx.x == 0) {
        float M[NB][NB];
        #pragma unroll
        for (int i = 0; i < NB; ++i)
            #pragma unroll
            for (int j = 0; j < NB; ++j)
                M[i][j] = expf(H_res[i * NB + j]);

        for (int it = 0; it < SINK_ITERS; ++it) {
            #pragma unroll
            for (int i = 0; i < NB; ++i) {
                float r = 1.0f / (M[i][0] + M[i][1] + M[i][2] + M[i][3] + EPS);
                #pragma unroll
                for (int j = 0; j < NB; ++j) M[i][j] *= r;
            }
            #pragma unroll
            for (int j = 0; j < NB; ++j) {
                float r = 1.0f / (M[0][j] + M[1][j] + M[2][j] + M[3][j] + EPS);
                #pragma unroll
                for (int i = 0; i < NB; ++i) M[i][j] *= r;
            }
        }
        #pragma unroll
        for (int i = 0; i < NB; ++i)
            #pragma unroll
            for (int j = 0; j < NB; ++j)
                ws[i * NB + j] = M[i][j];
        #pragma unroll
        for (int n = 0; n < NB; ++n) {
            ws[16 + n] = 1.0f / (1.0f + expf(-H_pre[n]));
            ws[20 + n] = 1.0f / (1.0f + expf(-H_post[n]));
        }
    }
}

// Kernel 2: software-pipelined. Each block owns 8 consecutive tokens;
// while token k is reduced+mixed+stored, token k+1's x loads are in flight.
// Raw s_barrier (lgkmcnt-only wait) keeps prefetch loads alive across the
// barrier; red[] is double-buffered so one barrier per phase is safe.
__global__ __launch_bounds__(TPB) void mhc_main(const float* __restrict__ x,
                                                const float* __restrict__ w,
                                                const float* __restrict__ ws,
                                                float* __restrict__ y)
{
    const int t = threadIdx.x;
    const int wave = t >> 6;
    const int lane = t & 63;

    // Uniform mixing scalars: constant offsets from a uniform pointer -> SGPRs
    const float H00 = ws[0],  H01 = ws[1],  H02 = ws[2],  H03 = ws[3];
    const float H10 = ws[4],  H11 = ws[5],  H12 = ws[6],  H13 = ws[7];
    const float H20 = ws[8],  H21 = ws[9],  H22 = ws[10], H23 = ws[11];
    const float H30 = ws[12], H31 = ws[13], H32 = ws[14], H33 = ws[15];
    const float pre0 = ws[16], pre1 = ws[17], pre2 = ws[18], pre3 = ws[19];
    const float ps0  = ws[20], ps1  = ws[21], ps2  = ws[22], ps3  = ws[23];

    __shared__ f32x4 red4[2][TPB / 64];   // [phase][wave] = 4 branch partials

    const f32x4 wv = ((const f32x4*)w)[t];
    const int b0 = blockIdx.x * TOK_PER_BLK;

    auto xload = [&](int b, f32x4& d0, f32x4& d1, f32x4& d2, f32x4& d3) {
        const f32x4* p = (const f32x4*)x + (size_t)b * (NB * CH / 4) + t;
        d0 = __builtin_nontemporal_load(p);
        d1 = __builtin_nontemporal_load(p + (CH / 4));
        d2 = __builtin_nontemporal_load(p + 2 * (CH / 4));
        d3 = __builtin_nontemporal_load(p + 3 * (CH / 4));
    };

    auto process = [&](int b, f32x4 x0, f32x4 x1, f32x4 x2, f32x4 x3, int ph) {
        float s0 = x0.x * x0.x + x0.y * x0.y + x0.z * x0.z + x0.w * x0.w;
        float s1 = x1.x * x1.x + x1.y * x1.y + x1.z * x1.z + x1.w * x1.w;
        float s2 = x2.x * x2.x + x2.y * x2.y + x2.z * x2.z + x2.w * x2.w;
        float s3 = x3.x * x3.x + x3.y * x3.y + x3.z * x3.z + x3.w * x3.w;
        #pragma unroll
        for (int m = 1; m < 64; m <<= 1) {
            s0 += __shfl_xor(s0, m);
            s1 += __shfl_xor(s1, m);
            s2 += __shfl_xor(s2, m);
            s3 += __shfl_xor(s3, m);
        }
        if (lane == 0) {
            f32x4 v = { s0, s1, s2, s3 };
            red4[ph][wave] = v;
        }

        // LDS-only barrier: do NOT drain vmcnt (prefetch loads stay in flight)
        __builtin_amdgcn_sched_barrier(0);
        asm volatile("s_waitcnt lgkmcnt(0)" ::: "memory");
        __builtin_amdgcn_s_barrier();
        __builtin_amdgcn_sched_barrier(0);

        f32x4 r0 = red4[ph][0], r1 = red4[ph][1], r2 = red4[ph][2], r3 = red4[ph][3];
        f32x4 r4 = red4[ph][4], r5 = red4[ph][5], r6 = red4[ph][6], r7 = red4[ph][7];
        float t0 = ((r0.x + r1.x) + (r2.x + r3.x)) + ((r4.x + r5.x) + (r6.x + r7.x));
        float t1 = ((r0.y + r1.y) + (r2.y + r3.y)) + ((r4.y + r5.y) + (r6.y + r7.y));
        float t2 = ((r0.z + r1.z) + (r2.z + r3.z)) + ((r4.z + r5.z) + (r6.z + r7.z));
        float t3 = ((r0.w + r1.w) + (r2.w + r3.w)) + ((r4.w + r5.w) + (r6.w + r7.w));

        const float a0 = pre0 * rsqrtf(t0 * (1.0f / CH) + EPS);
        const float a1 = pre1 * rsqrtf(t1 * (1.0f / CH) + EPS);
        const float a2 = pre2 * rsqrtf(t2 * (1.0f / CH) + EPS);
        const float a3 = pre3 * rsqrtf(t3 * (1.0f / CH) + EPS);

        f32x4 wu;
        wu.x = wv.x * (a0 * x0.x + a1 * x1.x + a2 * x2.x + a3 * x3.x);
        wu.y = wv.y * (a0 * x0.y + a1 * x1.y + a2 * x2.y + a3 * x3.y);
        wu.z = wv.z * (a0 * x0.z + a1 * x1.z + a2 * x2.z + a3 * x3.z);
        wu.w = wv.w * (a0 * x0.w + a1 * x1.w + a2 * x2.w + a3 * x3.w);

        f32x4* yp = (f32x4*)y + (size_t)b * (NB * CH / 4) + t;
        f32x4 o;
        o.x = H00 * x0.x + H01 * x1.x + H02 * x2.x + H03 * x3.x + ps0 * wu.x;
        o.y = H00 * x0.y + H01 * x1.y + H02 * x2.y + H03 * x3.y + ps0 * wu.y;
        o.z = H00 * x0.z + H01 * x1.z + H02 * x2.z + H03 * x3.z + ps0 * wu.z;
        o.w = H00 * x0.w + H01 * x1.w + H02 * x2.w + H03 * x3.w + ps0 * wu.w;
        __builtin_nontemporal_store(o, yp);
        o.x = H10 * x0.x + H11 * x1.x + H12 * x2.x + H13 * x3.x + ps1 * wu.x;
        o.y = H10 * x0.y + H11 * x1.y + H12 * x2.y + H13 * x3.y + ps1 * wu.y;
        o.z = H10 * x0.z + H11 * x1.z + H12 * x2.z + H13 * x3.z + ps1 * wu.z;
        o.w = H10 * x0.w + H11 * x1.w + H12 * x2.w + H13 * x3.w + ps1 * wu.w;
        __builtin_nontemporal_store(o, yp + (CH / 4));
        o.x = H20 * x0.x + H21 * x1.x + H22 * x2.x + H23 * x3.x + ps2 * wu.x;
        o.y = H20 * x0.y + H21 * x1.y + H22 * x2.y + H23 * x3.y + ps2 * wu.y;
        o.z = H20 * x0.z + H21 * x1.z + H22 * x2.z + H23 * x3.z + ps2 * wu.z;
        o.w = H20 * x0.w + H21 * x1.w + H22 * x2.w + H23 * x3.w + ps2 * wu.w;
        __builtin_nontemporal_store(o, yp + 2 * (CH / 4));
        o.x = H30 * x0.x + H31 * x1.x + H32 * x2.x + H33 * x3.x + ps3 * wu.x;
        o.y = H30 * x0.y + H31 * x1.y + H32 * x2.y + H33 * x3.y + ps3 * wu.y;
        o.z = H30 * x0.z + H31 * x1.z + H32 * x2.z + H33 * x3.z + ps3 * wu.z;
        o.w = H30 * x0.w + H31 * x1.w + H32 * x2.w + H33 * x3.w + ps3 * wu.w;
        __builtin_nontemporal_store(o, yp + 3 * (CH / 4));
    };

    f32x4 xA0, xA1, xA2, xA3, xB0, xB1, xB2, xB3;

    // Software pipeline over 8 tokens: prefetch k+1 before processing k.
    xload(b0 + 0, xA0, xA1, xA2, xA3);
    xload(b0 + 1, xB0, xB1, xB2, xB3);
    process(b0 + 0, xA0, xA1, xA2, xA3, 0);
    xload(b0 + 2, xA0, xA1, xA2, xA3);
    process(b0 + 1, xB0, xB1, xB2, xB3, 1);
    xload(b0 + 3, xB0, xB1, xB2, xB3);
    process(b0 + 2, xA0, xA1, xA2, xA3, 0);
    xload(b0 + 4, xA0, xA1, xA2, xA3);
    process(b0 + 3, xB0, xB1, xB2, xB3, 1);
    xload(b0 + 5, xB0, xB1, xB2, xB3);
    process(b0 + 4, xA0, xA1, xA2, xA3, 0);
    xload(b0 + 6, xA0, xA1, xA2, xA3);
    process(b0 + 5, xB0, xB1, xB2, xB3, 1);
    xload(b0 + 7, xB0, xB1, xB2, xB3);
    process(b0 + 6, xA0, xA1, xA2, xA3, 0);
    process(b0 + 7, xB0, xB1, xB2, xB3, 1);
}

extern "C" void kernel_launch(void* const* d_in, const int* in_sizes, int n_in,
                              void* d_out, int out_size, void* d_ws, size_t ws_size,
                              hipStream_t stream) {
    const float* x      = (const float*)d_in[0];   // [B, N, C]
    const float* wgt    = (const float*)d_in[1];   // [C]
    const float* h_pre  = (const float*)d_in[2];   // [N]
    const float* h_post = (const float*)d_in[3];   // [N]
    const float* h_res  = (const float*)d_in[4];   // [N, N]
    float* y  = (float*)d_out;                     // [B, N, C]
    float* ws = (float*)d_ws;                      // >= 24 floats

    mhc_sinkhorn<<<1, 64, 0, stream>>>(h_pre, h_post, h_res, ws);
    mhc_main<<<NBLK, TPB, 0, stream>>>(x, wgt, ws, y);
}

// Round 6
// 102.395 us; speedup vs baseline: 1.1522x; 1.0564x over previous
//
#include <hip/hip_runtime.h>
#include <math.h>

#define B_TOK 8192
#define NB 4
#define CH 2048
#define TPB 512            // 8 waves/block
#define NBLK 1024          // 8192 waves = exactly fills 256 CU * 32 wave slots
#define TOK_PER_BLK 8
#define SINK_ITERS 20
#define EPS 1e-5f

typedef float f32x4 __attribute__((ext_vector_type(4)));

__device__ __forceinline__ float bcast_first(float v) {
    return __uint_as_float(__builtin_amdgcn_readfirstlane(__float_as_uint(v)));
}
__device__ __forceinline__ float read_lane(float v, int l) {
    return __uint_as_float(__builtin_amdgcn_readlane(__float_as_uint(v), l));
}

// Single fused kernel.
//  - Lane-parallel 4x4 Sinkhorn per wave (lane e holds M[e>>2][e&3]; row/col
//    sums via shfl_xor 1,2 / 4,8), overlapped with the first 2 tokens' x loads.
//  - 8-token software pipeline per block; LDS-only barrier (lgkmcnt wait, no
//    vmcnt drain) with double-buffered red4 so prefetch loads stay in flight.
//  - x read exactly once (nt loads), y written exactly once (nt stores).
__global__ __launch_bounds__(TPB) void mhc_fused(
    const float* __restrict__ x,
    const float* __restrict__ w,
    const float* __restrict__ H_pre,
    const float* __restrict__ H_post,
    const float* __restrict__ H_res,
    float* __restrict__ y)
{
    const int t = threadIdx.x;
    const int wave = t >> 6;
    const int lane = t & 63;
    const int b0 = blockIdx.x * TOK_PER_BLK;

    __shared__ f32x4 red4[2][TPB / 64];

    // ---- Issue first loads BEFORE sinkhorn math (latency overlap) ----
    f32x4 xA0, xA1, xA2, xA3, xB0, xB1, xB2, xB3;
    auto xload = [&](int b, f32x4& d0, f32x4& d1, f32x4& d2, f32x4& d3) {
        const f32x4* p = (const f32x4*)x + (size_t)b * (NB * CH / 4) + t;
        d0 = __builtin_nontemporal_load(p);
        d1 = __builtin_nontemporal_load(p + (CH / 4));
        d2 = __builtin_nontemporal_load(p + 2 * (CH / 4));
        d3 = __builtin_nontemporal_load(p + 3 * (CH / 4));
    };
    xload(b0 + 0, xA0, xA1, xA2, xA3);
    xload(b0 + 1, xB0, xB1, xB2, xB3);
    const f32x4 wv = ((const f32x4*)w)[t];

    // ---- Lane-parallel Sinkhorn (runs while the loads above are in flight) --
    const int e = lane & 15;          // matrix entry; 4 copies per wave
    float v = expf(H_res[e]);         // M[e>>2][e&3]
    #pragma unroll 1
    for (int it = 0; it < SINK_ITERS; ++it) {
        // row normalize: sum over j (low 2 bits of e)
        float s = v + __shfl_xor(v, 1);
        s += __shfl_xor(s, 2);
        v *= __builtin_amdgcn_rcpf(s + EPS);
        // col normalize: sum over i (bits 2-3 of e)
        s = v + __shfl_xor(v, 4);
        s += __shfl_xor(s, 8);
        v *= __builtin_amdgcn_rcpf(s + EPS);
    }
    // Broadcast the 16 entries to SGPRs
    const float H00 = read_lane(v, 0),  H01 = read_lane(v, 1),
                H02 = read_lane(v, 2),  H03 = read_lane(v, 3);
    const float H10 = read_lane(v, 4),  H11 = read_lane(v, 5),
                H12 = read_lane(v, 6),  H13 = read_lane(v, 7);
    const float H20 = read_lane(v, 8),  H21 = read_lane(v, 9),
                H22 = read_lane(v, 10), H23 = read_lane(v, 11);
    const float H30 = read_lane(v, 12), H31 = read_lane(v, 13),
                H32 = read_lane(v, 14), H33 = read_lane(v, 15);

    // Sigmoids (uniform; scalar loads of 8 floats)
    const float pre0 = bcast_first(1.0f / (1.0f + expf(-H_pre[0])));
    const float pre1 = bcast_first(1.0f / (1.0f + expf(-H_pre[1])));
    const float pre2 = bcast_first(1.0f / (1.0f + expf(-H_pre[2])));
    const float pre3 = bcast_first(1.0f / (1.0f + expf(-H_pre[3])));
    const float ps0  = bcast_first(1.0f / (1.0f + expf(-H_post[0])));
    const float ps1  = bcast_first(1.0f / (1.0f + expf(-H_post[1])));
    const float ps2  = bcast_first(1.0f / (1.0f + expf(-H_post[2])));
    const float ps3  = bcast_first(1.0f / (1.0f + expf(-H_post[3])));

    auto process = [&](int b, f32x4 x0, f32x4 x1, f32x4 x2, f32x4 x3, int ph) {
        float s0 = x0.x * x0.x + x0.y * x0.y + x0.z * x0.z + x0.w * x0.w;
        float s1 = x1.x * x1.x + x1.y * x1.y + x1.z * x1.z + x1.w * x1.w;
        float s2 = x2.x * x2.x + x2.y * x2.y + x2.z * x2.z + x2.w * x2.w;
        float s3 = x3.x * x3.x + x3.y * x3.y + x3.z * x3.z + x3.w * x3.w;
        #pragma unroll
        for (int m = 1; m < 64; m <<= 1) {
            s0 += __shfl_xor(s0, m);
            s1 += __shfl_xor(s1, m);
            s2 += __shfl_xor(s2, m);
            s3 += __shfl_xor(s3, m);
        }
        if (lane == 0) {
            f32x4 pv = { s0, s1, s2, s3 };
            red4[ph][wave] = pv;
        }

        // LDS-only barrier: do NOT drain vmcnt (prefetch loads stay in flight)
        __builtin_amdgcn_sched_barrier(0);
        asm volatile("s_waitcnt lgkmcnt(0)" ::: "memory");
        __builtin_amdgcn_s_barrier();
        __builtin_amdgcn_sched_barrier(0);

        f32x4 r0 = red4[ph][0], r1 = red4[ph][1], r2 = red4[ph][2], r3 = red4[ph][3];
        f32x4 r4 = red4[ph][4], r5 = red4[ph][5], r6 = red4[ph][6], r7 = red4[ph][7];
        float t0 = ((r0.x + r1.x) + (r2.x + r3.x)) + ((r4.x + r5.x) + (r6.x + r7.x));
        float t1 = ((r0.y + r1.y) + (r2.y + r3.y)) + ((r4.y + r5.y) + (r6.y + r7.y));
        float t2 = ((r0.z + r1.z) + (r2.z + r3.z)) + ((r4.z + r5.z) + (r6.z + r7.z));
        float t3 = ((r0.w + r1.w) + (r2.w + r3.w)) + ((r4.w + r5.w) + (r6.w + r7.w));

        const float a0 = pre0 * rsqrtf(t0 * (1.0f / CH) + EPS);
        const float a1 = pre1 * rsqrtf(t1 * (1.0f / CH) + EPS);
        const float a2 = pre2 * rsqrtf(t2 * (1.0f / CH) + EPS);
        const float a3 = pre3 * rsqrtf(t3 * (1.0f / CH) + EPS);

        f32x4 wu;
        wu.x = wv.x * (a0 * x0.x + a1 * x1.x + a2 * x2.x + a3 * x3.x);
        wu.y = wv.y * (a0 * x0.y + a1 * x1.y + a2 * x2.y + a3 * x3.y);
        wu.z = wv.z * (a0 * x0.z + a1 * x1.z + a2 * x2.z + a3 * x3.z);
        wu.w = wv.w * (a0 * x0.w + a1 * x1.w + a2 * x2.w + a3 * x3.w);

        f32x4* yp = (f32x4*)y + (size_t)b * (NB * CH / 4) + t;
        f32x4 o;
        o.x = H00 * x0.x + H01 * x1.x + H02 * x2.x + H03 * x3.x + ps0 * wu.x;
        o.y = H00 * x0.y + H01 * x1.y + H02 * x2.y + H03 * x3.y + ps0 * wu.y;
        o.z = H00 * x0.z + H01 * x1.z + H02 * x2.z + H03 * x3.z + ps0 * wu.z;
        o.w = H00 * x0.w + H01 * x1.w + H02 * x2.w + H03 * x3.w + ps0 * wu.w;
        __builtin_nontemporal_store(o, yp);
        o.x = H10 * x0.x + H11 * x1.x + H12 * x2.x + H13 * x3.x + ps1 * wu.x;
        o.y = H10 * x0.y + H11 * x1.y + H12 * x2.y + H13 * x3.y + ps1 * wu.y;
        o.z = H10 * x0.z + H11 * x1.z + H12 * x2.z + H13 * x3.z + ps1 * wu.z;
        o.w = H10 * x0.w + H11 * x1.w + H12 * x2.w + H13 * x3.w + ps1 * wu.w;
        __builtin_nontemporal_store(o, yp + (CH / 4));
        o.x = H20 * x0.x + H21 * x1.x + H22 * x2.x + H23 * x3.x + ps2 * wu.x;
        o.y = H20 * x0.y + H21 * x1.y + H22 * x2.y + H23 * x3.y + ps2 * wu.y;
        o.z = H20 * x0.z + H21 * x1.z + H22 * x2.z + H23 * x3.z + ps2 * wu.z;
        o.w = H20 * x0.w + H21 * x1.w + H22 * x2.w + H23 * x3.w + ps2 * wu.w;
        __builtin_nontemporal_store(o, yp + 2 * (CH / 4));
        o.x = H30 * x0.x + H31 * x1.x + H32 * x2.x + H33 * x3.x + ps3 * wu.x;
        o.y = H30 * x0.y + H31 * x1.y + H32 * x2.y + H33 * x3.y + ps3 * wu.y;
        o.z = H30 * x0.z + H31 * x1.z + H32 * x2.z + H33 * x3.z + ps3 * wu.z;
        o.w = H30 * x0.w + H31 * x1.w + H32 * x2.w + H33 * x3.w + ps3 * wu.w;
        __builtin_nontemporal_store(o, yp + 3 * (CH / 4));
    };

    // Software pipeline over 8 tokens: prefetch k+1 before processing k.
    process(b0 + 0, xA0, xA1, xA2, xA3, 0);
    xload(b0 + 2, xA0, xA1, xA2, xA3);
    process(b0 + 1, xB0, xB1, xB2, xB3, 1);
    xload(b0 + 3, xB0, xB1, xB2, xB3);
    process(b0 + 2, xA0, xA1, xA2, xA3, 0);
    xload(b0 + 4, xA0, xA1, xA2, xA3);
    process(b0 + 3, xB0, xB1, xB2, xB3, 1);
    xload(b0 + 5, xB0, xB1, xB2, xB3);
    process(b0 + 4, xA0, xA1, xA2, xA3, 0);
    xload(b0 + 6, xA0, xA1, xA2, xA3);
    process(b0 + 5, xB0, xB1, xB2, xB3, 1);
    xload(b0 + 7, xB0, xB1, xB2, xB3);
    process(b0 + 6, xA0, xA1, xA2, xA3, 0);
    process(b0 + 7, xB0, xB1, xB2, xB3, 1);
}

extern "C" void kernel_launch(void* const* d_in, const int* in_sizes, int n_in,
                              void* d_out, int out_size, void* d_ws, size_t ws_size,
                              hipStream_t stream) {
    const float* x      = (const float*)d_in[0];   // [B, N, C]
    const float* wgt    = (const float*)d_in[1];   // [C]
    const float* h_pre  = (const float*)d_in[2];   // [N]
    const float* h_post = (const float*)d_in[3];   // [N]
    const float* h_res  = (const float*)d_in[4];   // [N, N]
    float* y = (float*)d_out;                      // [B, N, C]

    mhc_fused<<<NBLK, TPB, 0, stream>>>(x, wgt, h_pre, h_post, h_res, y);
}